// Round 2
// baseline (26244.229 us; speedup 1.0000x reference)
//
#include <hip/hip_runtime.h>
#include <cstddef>

// Problem constants (fixed by the reference)
static constexpr int Nn   = 50000;    // nodes
static constexpr int Ee   = 800000;   // edges
static constexpr int LGEe = 1600000;  // line-graph edges

// ---------- ws layout (LEAN, peak 442.4 MB) ----------
// BUF     : E*128 f32   z1 -> pre-relu h1; after phase 2 it is dead and the
//                       8 node-phase arrays (N*128 each) are carved from it.
// agg     : N*128 f32   EdgeToNode accumulator (must coexist with BUF)
// deg_lg  : E f32, deg_n/deg_r/mb/den : N f32 each, score : E f32

__device__ __forceinline__ void fadd(float* p, float v) {
  unsafeAtomicAdd(p, v);  // native global_atomic_add_f32
}

__global__ __launch_bounds__(256)
void k_fill(float* __restrict__ p, float v, int n) {
  int i = blockIdx.x * 256 + threadIdx.x;
  if (i < n) p[i] = v;
}

__global__ __launch_bounds__(256)
void k_deg(const int* __restrict__ idx, float* __restrict__ deg, int n) {
  int i = blockIdx.x * 256 + threadIdx.x;
  if (i < n) fadd(&deg[idx[i]], 1.0f);
}

// C[M x 128] = act( rowscale(reluA(A)) @ W ),  A: M x K (K%32==0), W: K x 128
// act: 0 none, 1 relu, 2 leaky(0.2). dgA: per-row scale 1/max(dgA[r],1).
__global__ __launch_bounds__(256)
void k_gemm128(int M, const float* __restrict__ A, int K,
               const float* __restrict__ W, const float* __restrict__ dgA,
               int reluA, int act, float* __restrict__ C)
{
  __shared__ float sA[32][132];
  __shared__ float sW[32][132];
  const int t = threadIdx.x, tr = t >> 4, tc = t & 15;
  const int row0 = blockIdx.x * 128;
  float acc[8][8];
  #pragma unroll
  for (int i = 0; i < 8; ++i)
    #pragma unroll
    for (int j = 0; j < 8; ++j) acc[i][j] = 0.f;

  #pragma unroll 1
  for (int k0 = 0; k0 < K; k0 += 32) {
    __syncthreads();
    #pragma unroll
    for (int j = 0; j < 4; ++j) {
      int idx = t * 4 + j * 1024;
      int r = idx >> 5, kk = idx & 31;        // kk in {0,4,...,28}
      int gr = row0 + r; if (gr > M - 1) gr = M - 1;
      float4 va = *(const float4*)(A + (size_t)gr * K + k0 + kk);
      if (reluA) {
        va.x = fmaxf(va.x, 0.f); va.y = fmaxf(va.y, 0.f);
        va.z = fmaxf(va.z, 0.f); va.w = fmaxf(va.w, 0.f);
      }
      if (dgA) {
        float sc = 1.0f / fmaxf(dgA[gr], 1.0f);
        va.x *= sc; va.y *= sc; va.z *= sc; va.w *= sc;
      }
      sA[kk + 0][r] = va.x; sA[kk + 1][r] = va.y;
      sA[kk + 2][r] = va.z; sA[kk + 3][r] = va.w;
    }
    #pragma unroll
    for (int j = 0; j < 4; ++j) {
      int idx = t * 4 + j * 1024;
      int kk = idx >> 7, c = idx & 127;
      *(float4*)&sW[kk][c] = *(const float4*)(W + (size_t)(k0 + kk) * 128 + c);
    }
    __syncthreads();
    #pragma unroll
    for (int kk = 0; kk < 32; ++kk) {
      float a[8], w[8];
      *(float4*)&a[0] = *(const float4*)&sA[kk][tr * 8];
      *(float4*)&a[4] = *(const float4*)&sA[kk][tr * 8 + 4];
      *(float4*)&w[0] = *(const float4*)&sW[kk][tc * 8];
      *(float4*)&w[4] = *(const float4*)&sW[kk][tc * 8 + 4];
      #pragma unroll
      for (int i = 0; i < 8; ++i)
        #pragma unroll
        for (int j = 0; j < 8; ++j)
          acc[i][j] = fmaf(a[i], w[j], acc[i][j]);
    }
  }
  #pragma unroll 1
  for (int i = 0; i < 8; ++i) {
    int gr = row0 + tr * 8 + i;
    if (gr >= M) return;
    float o[8];
    #pragma unroll
    for (int j = 0; j < 8; ++j) {
      float vv = acc[i][j];
      if (act == 1)      vv = fmaxf(vv, 0.f);
      else if (act == 2) vv = vv > 0.f ? vv : vv * 0.2f;
      o[j] = vv;
    }
    *(float4*)(C + (size_t)gr * 128 + tc * 8)     = *(const float4*)&o[0];
    *(float4*)(C + (size_t)gr * 128 + tc * 8 + 4) = *(const float4*)&o[4];
  }
}

// Gather-GEMM-scatter:  for m in [0,M):
//   row = reluA(A[gidx?gidx[m]:m]) @ W                (K x 128)
//   d   = didx ? didx[m] : m ;  sc = deg ? 1/max(deg[d],1) : 1
//   OUT[map1?map1[d]:d] += row*sc ; if map2: OUT[map2[d]] += row*sc   (atomic)
__global__ __launch_bounds__(256)
void k_ggs(int M, const float* __restrict__ A, int K, const float* __restrict__ W,
           const int* __restrict__ gidx, int reluA,
           const int* __restrict__ didx, const float* __restrict__ deg,
           const int* __restrict__ map1, const int* __restrict__ map2,
           float* __restrict__ OUT)
{
  __shared__ float sA[32][132];
  __shared__ float sW[32][132];
  const int t = threadIdx.x, tr = t >> 4, tc = t & 15;
  const int row0 = blockIdx.x * 128;
  float acc[8][8];
  #pragma unroll
  for (int i = 0; i < 8; ++i)
    #pragma unroll
    for (int j = 0; j < 8; ++j) acc[i][j] = 0.f;

  #pragma unroll 1
  for (int k0 = 0; k0 < K; k0 += 32) {
    __syncthreads();
    #pragma unroll
    for (int j = 0; j < 4; ++j) {
      int idx = t * 4 + j * 1024;
      int r = idx >> 5, kk = idx & 31;
      int gm = row0 + r; if (gm > M - 1) gm = M - 1;
      int ga = gidx ? gidx[gm] : gm;
      float4 va = *(const float4*)(A + (size_t)ga * K + k0 + kk);
      if (reluA) {
        va.x = fmaxf(va.x, 0.f); va.y = fmaxf(va.y, 0.f);
        va.z = fmaxf(va.z, 0.f); va.w = fmaxf(va.w, 0.f);
      }
      sA[kk + 0][r] = va.x; sA[kk + 1][r] = va.y;
      sA[kk + 2][r] = va.z; sA[kk + 3][r] = va.w;
    }
    #pragma unroll
    for (int j = 0; j < 4; ++j) {
      int idx = t * 4 + j * 1024;
      int kk = idx >> 7, c = idx & 127;
      *(float4*)&sW[kk][c] = *(const float4*)(W + (size_t)(k0 + kk) * 128 + c);
    }
    __syncthreads();
    #pragma unroll
    for (int kk = 0; kk < 32; ++kk) {
      float a[8], w[8];
      *(float4*)&a[0] = *(const float4*)&sA[kk][tr * 8];
      *(float4*)&a[4] = *(const float4*)&sA[kk][tr * 8 + 4];
      *(float4*)&w[0] = *(const float4*)&sW[kk][tc * 8];
      *(float4*)&w[4] = *(const float4*)&sW[kk][tc * 8 + 4];
      #pragma unroll
      for (int i = 0; i < 8; ++i)
        #pragma unroll
        for (int j = 0; j < 8; ++j)
          acc[i][j] = fmaf(a[i], w[j], acc[i][j]);
    }
  }
  #pragma unroll 1
  for (int i = 0; i < 8; ++i) {
    int gm = row0 + tr * 8 + i;
    if (gm >= M) return;
    int d = didx ? didx[gm] : gm;
    float sc = deg ? 1.0f / fmaxf(deg[d], 1.0f) : 1.0f;
    int t1 = map1 ? map1[d] : d;
    float* p1 = OUT + (size_t)t1 * 128 + tc * 8;
    #pragma unroll
    for (int j = 0; j < 8; ++j) fadd(p1 + j, acc[i][j] * sc);
    if (map2) {
      int t2 = map2[d];
      float* p2 = OUT + (size_t)t2 * 128 + tc * 8;
      #pragma unroll
      for (int j = 0; j < 8; ++j) fadd(p2 + j, acc[i][j] * sc);
    }
  }
}

// out[dst[e]] += in[src[e]] / max(deg[dst[e]],1)   (128-wide rows)
__global__ __launch_bounds__(256)
void k_rowscat(const float* __restrict__ in, float* __restrict__ out,
               const int* __restrict__ src, const int* __restrict__ dst,
               const float* __restrict__ deg, long total) {
  long idx = (long)blockIdx.x * 256 + threadIdx.x;
  if (idx >= total) return;
  int e = (int)(idx >> 7), c = (int)(idx & 127);
  int d = dst[e];
  float sc = 1.0f / fmaxf(deg[d], 1.0f);
  fadd(out + ((size_t)d << 7) + c, in[((size_t)src[e] << 7) + c] * sc);
}

__global__ __launch_bounds__(256)
void k_score(const float* __restrict__ q, const float* __restrict__ k,
             const int* __restrict__ src, const int* __restrict__ dst,
             float* __restrict__ score, int n) {
  int e = blockIdx.x * 256 + threadIdx.x;
  if (e >= n) return;
  const float4* qr = (const float4*)(q + (size_t)dst[e] * 128);
  const float4* kr = (const float4*)(k + (size_t)src[e] * 128);
  float s = 0.f;
  #pragma unroll 4
  for (int i = 0; i < 32; ++i) {
    float4 a = qr[i], b = kr[i];
    s = fmaf(a.x, b.x, s); s = fmaf(a.y, b.y, s);
    s = fmaf(a.z, b.z, s); s = fmaf(a.w, b.w, s);
  }
  s *= 0.088388347648318447f;  // 1/sqrt(128)
  score[e] = s > 0.f ? s : s * 0.2f;  // leaky 0.2
}

// float atomic max via int/uint monotone trick (init very negative)
__global__ __launch_bounds__(256)
void k_smax(const float* __restrict__ score, const int* __restrict__ dst,
            float* __restrict__ m, int n) {
  int e = blockIdx.x * 256 + threadIdx.x;
  if (e >= n) return;
  float v = score[e]; int d = dst[e];
  if (v >= 0.f) atomicMax((int*)(m + d), __float_as_int(v));
  else          atomicMin((unsigned int*)(m + d), __float_as_uint(v));
}

__global__ __launch_bounds__(256)
void k_exden(float* __restrict__ score, const int* __restrict__ dst,
             const float* __restrict__ m, float* __restrict__ den, int n) {
  int e = blockIdx.x * 256 + threadIdx.x;
  if (e >= n) return;
  int d = dst[e];
  float ex = expf(score[e] - m[d]);
  score[e] = ex;
  fadd(den + d, ex);
}

__global__ __launch_bounds__(256)
void k_alpha(float* __restrict__ score, const float* __restrict__ den,
             const int* __restrict__ dst, int n) {
  int e = blockIdx.x * 256 + threadIdx.x;
  if (e >= n) return;
  score[e] = score[e] / fmaxf(den[dst[e]], 1e-9f);
}

__global__ __launch_bounds__(256)
void k_attn_scatter(const float* __restrict__ alpha, const float* __restrict__ v,
                    const int* __restrict__ src, const int* __restrict__ dst,
                    float* __restrict__ acc, long total) {
  long idx = (long)blockIdx.x * 256 + threadIdx.x;
  if (idx >= total) return;
  int e = (int)(idx >> 7), c = (int)(idx & 127);
  fadd(acc + ((size_t)dst[e] << 7) + c,
       alpha[e] * v[((size_t)src[e] << 7) + c]);
}

// logits = attn @ W_out (128x64), then row log_softmax. One wave per row.
__global__ __launch_bounds__(256)
void k_out(const float* __restrict__ attn, const float* __restrict__ Wout,
           float* __restrict__ out, int n) {
  __shared__ float sW[128 * 64];
  for (int i = threadIdx.x; i < 128 * 64; i += 256) sW[i] = Wout[i];
  __syncthreads();
  int wave = threadIdx.x >> 6, lane = threadIdx.x & 63;
  int row = blockIdx.x * 4 + wave;
  if (row >= n) return;
  const float* a = attn + (size_t)row * 128;
  float z = 0.f;
  #pragma unroll 8
  for (int k = 0; k < 128; ++k) z = fmaf(a[k], sW[k * 64 + lane], z);
  float mx = z;
  #pragma unroll
  for (int off = 32; off; off >>= 1) mx = fmaxf(mx, __shfl_xor(mx, off));
  float ee = expf(z - mx);
  float ss = ee;
  #pragma unroll
  for (int off = 32; off; off >>= 1) ss += __shfl_xor(ss, off);
  out[(size_t)row * 64 + lane] = z - mx - logf(ss);
}

extern "C" void kernel_launch(void* const* d_in, const int* in_sizes, int n_in,
                              void* d_out, int out_size, void* d_ws, size_t ws_size,
                              hipStream_t stream) {
  (void)in_sizes; (void)n_in; (void)out_size;
  const float* x        = (const float*)d_in[0];
  const float* et       = (const float*)d_in[1];
  const int*   H0       = (const int*)d_in[2];
  const int*   H1       = H0 + Ee;
  const int*   src      = (const int*)d_in[3];
  const int*   dst      = src + Ee;
  const int*   src_lg   = (const int*)d_in[4];
  const int*   dst_lg   = src_lg + LGEe;
  const float* W_tsa1_s = (const float*)d_in[5];
  const float* W_tsa1_n = (const float*)d_in[6];
  const float* W_tsa2_s = (const float*)d_in[7];
  const float* W_tsa2_n = (const float*)d_in[8];
  const float* W_etn    = (const float*)d_in[9];
  const float* W_eg_lin = (const float*)d_in[10];
  const float* W_ea_s   = (const float*)d_in[11];
  const float* W_ea_n   = (const float*)d_in[12];
  const float* W_an1_s  = (const float*)d_in[13];
  const float* W_an1_n  = (const float*)d_in[14];
  const float* W_an2_s  = (const float*)d_in[15];
  const float* W_an2_n  = (const float*)d_in[16];
  const float* Wq       = (const float*)d_in[17];
  const float* Wk       = (const float*)d_in[18];
  const float* Wv       = (const float*)d_in[19];
  const float* W_out    = (const float*)d_in[20];
  float* out = (float*)d_out;

  // ---- workspace carve (peak 442.4 MB) ----
  const size_t NH = (size_t)Nn * 128;
  const size_t needF = (size_t)Ee * 128 + NH + (size_t)Ee + 4 * (size_t)Nn + (size_t)Ee;
  if (ws_size < needF * sizeof(float)) return;  // diagnostic: clean absmax-fail, not a crash

  float* BUF    = (float*)d_ws;               // E*128 (z1 / pre-relu h1)
  float* agg    = BUF + (size_t)Ee * 128;     // N*128
  float* deg_lg = agg + NH;                   // E
  float* deg_n  = deg_lg + Ee;                // N
  float* deg_r  = deg_n + Nn;                 // N
  float* mb     = deg_r + Nn;                 // N
  float* den    = mb + Nn;                    // N
  float* score  = den + Nn;                   // E
  // node arrays carved from BUF (dead after phase 2)
  float* edge_repr = BUF + 0 * NH;
  float* aggr_edge = BUF + 1 * NH;
  float* hn        = BUF + 2 * NH;
  float* hn2       = BUF + 3 * NH;
  float* qb        = BUF + 4 * NH;
  float* kb        = BUF + 5 * NH;
  float* vb        = BUF + 6 * NH;
  float* tmp       = BUF + 7 * NH;

  const int gE  = Ee / 128;      // 6250 (exact)
  const int gLG = LGEe / 128;    // 12500 (exact)
  const int gN  = (Nn + 127) / 128;
  auto cdiv = [](long a, long b) { return (int)((a + b - 1) / b); };

  // ---- Phase 1: TSA layer 1 (line graph) -> BUF = pre-relu h1 ----
  hipMemsetAsync(deg_lg, 0, (size_t)Ee * 4, stream);
  k_deg<<<cdiv(LGEe, 256), 256, 0, stream>>>(dst_lg, deg_lg, LGEe);
  // z1 = et @ W_tsa1_s
  k_gemm128<<<gE, 256, 0, stream>>>(Ee, et, 64, W_tsa1_s, nullptr, 0, 0, BUF);
  // BUF[dst_lg] += (et[src_lg] @ W_tsa1_n) / deg_lg[dst_lg]
  k_ggs<<<gLG, 256, 0, stream>>>(LGEe, et, 64, W_tsa1_n, src_lg, 0,
                                 dst_lg, deg_lg, nullptr, nullptr, BUF);

  // ---- Phase 2: TSA layer 2 fused with EdgeToNodeConv (h2 never materialized) ----
  hipMemsetAsync(agg, 0, NH * 4, stream);
  hipMemsetAsync(deg_n, 0, (size_t)Nn * 4, stream);
  k_deg<<<cdiv(Ee, 256), 256, 0, stream>>>(H0, deg_n, Ee);
  k_deg<<<cdiv(Ee, 256), 256, 0, stream>>>(H1, deg_n, Ee);
  // self term: agg[H0[m]] += relu(h1[m])@W_tsa2_s ; same for H1
  k_ggs<<<gE, 256, 0, stream>>>(Ee, BUF, 128, W_tsa2_s, nullptr, 1,
                                nullptr, nullptr, H0, H1, agg);
  // nbr term: d=dst_lg[m]; agg[H0[d]] += (relu(h1[src_lg[m]])@W_tsa2_n)/deg_lg[d]; same H1
  k_ggs<<<gLG, 256, 0, stream>>>(LGEe, BUF, 128, W_tsa2_n, src_lg, 1,
                                 dst_lg, deg_lg, H0, H1, agg);
  // BUF is dead now; node arrays live in it.
  k_gemm128<<<gN, 256, 0, stream>>>(Nn, agg, 128, W_etn, deg_n, 0, 2, tmp);       // leaky((agg/deg)@W_etn)
  k_gemm128<<<gN, 256, 0, stream>>>(Nn, tmp, 128, W_eg_lin, nullptr, 0, 0, edge_repr);

  // ---- Phase 3: edge_aggr SAGE (raw graph), linearity: pretransform + rowscat ----
  hipMemsetAsync(deg_r, 0, (size_t)Nn * 4, stream);
  k_deg<<<cdiv(Ee, 256), 256, 0, stream>>>(dst, deg_r, Ee);
  k_gemm128<<<gN, 256, 0, stream>>>(Nn, edge_repr, 128, W_ea_s, nullptr, 0, 0, aggr_edge);
  k_gemm128<<<gN, 256, 0, stream>>>(Nn, edge_repr, 128, W_ea_n, nullptr, 0, 0, tmp);
  k_rowscat<<<cdiv((long)Ee * 128, 256), 256, 0, stream>>>(tmp, aggr_edge, src, dst, deg_r, (long)Ee * 128);

  // ---- Phase 4: attr_node_model (2-layer SAGE); hn kept PRE-relu, relu on read ----
  k_gemm128<<<gN, 256, 0, stream>>>(Nn, x, 256, W_an1_s, nullptr, 0, 0, hn);
  k_gemm128<<<gN, 256, 0, stream>>>(Nn, x, 256, W_an1_n, nullptr, 0, 0, tmp);
  k_rowscat<<<cdiv((long)Ee * 128, 256), 256, 0, stream>>>(tmp, hn, src, dst, deg_r, (long)Ee * 128);
  k_gemm128<<<gN, 256, 0, stream>>>(Nn, hn, 128, W_an2_s, nullptr, 1, 0, hn2);
  k_gemm128<<<gN, 256, 0, stream>>>(Nn, hn, 128, W_an2_n, nullptr, 1, 0, tmp);
  k_rowscat<<<cdiv((long)Ee * 128, 256), 256, 0, stream>>>(tmp, hn2, src, dst, deg_r, (long)Ee * 128);

  // ---- Phase 5: MixAttention ----
  k_gemm128<<<gN, 256, 0, stream>>>(Nn, hn2, 128, Wq, nullptr, 0, 0, qb);
  k_gemm128<<<gN, 256, 0, stream>>>(Nn, aggr_edge, 128, Wk, nullptr, 0, 0, kb);
  k_gemm128<<<gN, 256, 0, stream>>>(Nn, aggr_edge, 128, Wv, nullptr, 0, 0, vb);
  k_score<<<cdiv(Ee, 256), 256, 0, stream>>>(qb, kb, src, dst, score, Ee);
  k_fill<<<cdiv(Nn, 256), 256, 0, stream>>>(mb, -1e30f, Nn);
  hipMemsetAsync(den, 0, (size_t)Nn * 4, stream);
  k_smax<<<cdiv(Ee, 256), 256, 0, stream>>>(score, dst, mb, Ee);
  k_exden<<<cdiv(Ee, 256), 256, 0, stream>>>(score, dst, mb, den, Ee);
  k_alpha<<<cdiv(Ee, 256), 256, 0, stream>>>(score, den, dst, Ee);
  k_attn_scatter<<<cdiv((long)Ee * 128, 256), 256, 0, stream>>>(
      score, vb, src, dst, hn2, (long)Ee * 128);

  // ---- Phase 6: classifier + log_softmax ----
  k_out<<<cdiv(Nn, 4), 256, 0, stream>>>(hn2, W_out, out, Nn);
}

// Round 3
// 4604.259 us; speedup vs baseline: 5.7000x; 5.7000x over previous
//
#include <hip/hip_runtime.h>
#include <cstddef>

static constexpr int Nn   = 50000;
static constexpr int Ee   = 800000;
static constexpr int LGEe = 1600000;

__device__ __forceinline__ float bf2f(unsigned int u16) {
  return __uint_as_float(u16 << 16);
}
__device__ __forceinline__ unsigned int f2bf(float f) {
  unsigned int u = __float_as_uint(f);
  u += 0x7fffu + ((u >> 16) & 1u);   // RNE
  return u >> 16;
}

// ---------------- CSR build kernels ----------------
__global__ __launch_bounds__(256)
void k_count_direct(const int* __restrict__ idx, int* __restrict__ cnt, int n) {
  int i = blockIdx.x * 256 + threadIdx.x;
  if (i < n) atomicAdd(&cnt[idx[i]], 1);
}
__global__ __launch_bounds__(256)
void k_count_comp(const int* __restrict__ Hrow, const int* __restrict__ dlg,
                  int* __restrict__ cnt, int n) {
  int i = blockIdx.x * 256 + threadIdx.x;
  if (i < n) atomicAdd(&cnt[Hrow[dlg[i]]], 1);
}
__global__ __launch_bounds__(256)
void k_scan1(const int* __restrict__ in, int* __restrict__ out,
             int* __restrict__ bsum, int n) {
  __shared__ int sd[256];
  int tid = threadIdx.x;
  int base = blockIdx.x * 1024 + tid * 4;
  int4 v = {0, 0, 0, 0};
  if (base < n) v = *(const int4*)(in + base);   // n % 4 == 0 for all uses
  int s = v.x + v.y + v.z + v.w;
  sd[tid] = s; __syncthreads();
  for (int off = 1; off < 256; off <<= 1) {
    int t_ = (tid >= off) ? sd[tid - off] : 0; __syncthreads();
    sd[tid] += t_; __syncthreads();
  }
  int excl = sd[tid] - s;
  if (base < n) {
    int4 o; o.x = excl; o.y = o.x + v.x; o.z = o.y + v.y; o.w = o.z + v.z;
    *(int4*)(out + base) = o;
  }
  if (tid == 255) bsum[blockIdx.x] = sd[255];
}
__global__ __launch_bounds__(1024)
void k_scan2(int* __restrict__ b, int nb) {
  __shared__ int sd[1024];
  int tid = threadIdx.x;
  int v = (tid < nb) ? b[tid] : 0;
  sd[tid] = v; __syncthreads();
  for (int off = 1; off < 1024; off <<= 1) {
    int t_ = (tid >= off) ? sd[tid - off] : 0; __syncthreads();
    sd[tid] += t_; __syncthreads();
  }
  if (tid < nb) b[tid] = sd[tid] - v;
}
__global__ __launch_bounds__(256)
void k_scan3(int* __restrict__ out, const int* __restrict__ bsum, int n, int total) {
  int i = blockIdx.x * 256 + threadIdx.x;
  if (i < n) out[i] += bsum[i >> 10];
  if (i == 0) out[n] = total;
}
__global__ __launch_bounds__(256)
void k_fillA(const int* __restrict__ dlg, const int* __restrict__ slg,
             const int* __restrict__ ptr, int* __restrict__ cur,
             int* __restrict__ ent, int n) {
  int m = blockIdx.x * 256 + threadIdx.x;
  if (m >= n) return;
  int d = dlg[m];
  int pos = ptr[d] + atomicAdd(&cur[d], 1);
  ent[pos] = slg[m];
}
__global__ __launch_bounds__(256)
void k_fillB(const int* __restrict__ Hrow, const int* __restrict__ dlg,
             const int* __restrict__ slg, const int* __restrict__ ptrA,
             const int* __restrict__ ptrB, int* __restrict__ cur,
             int* __restrict__ entS, float* __restrict__ entW, int n) {
  int m = blockIdx.x * 256 + threadIdx.x;
  if (m >= n) return;
  int d = dlg[m];
  int seg = Hrow[d];
  int pos = ptrB[seg] + atomicAdd(&cur[seg], 1);
  entS[pos] = slg[m];
  int la = ptrA[d + 1] - ptrA[d];
  entW[pos] = 1.0f / (float)max(la, 1);
}
__global__ __launch_bounds__(256)
void k_fillC(const int* __restrict__ Hrow, const int* __restrict__ ptr,
             int* __restrict__ cur, int* __restrict__ ent, int n) {
  int e = blockIdx.x * 256 + threadIdx.x;
  if (e >= n) return;
  int seg = Hrow[e];
  int pos = ptr[seg] + atomicAdd(&cur[seg], 1);
  ent[pos] = e;
}
__global__ __launch_bounds__(256)
void k_fillD(const int* __restrict__ dstA, const int* __restrict__ srcA,
             const int* __restrict__ ptr, int* __restrict__ cur,
             int* __restrict__ ent, int n) {
  int e = blockIdx.x * 256 + threadIdx.x;
  if (e >= n) return;
  int seg = dstA[e];
  int pos = ptr[seg] + atomicAdd(&cur[seg], 1);
  ent[pos] = srcA[e];
}
__global__ __launch_bounds__(256)
void k_rdeg(const int* __restrict__ ptr, float* __restrict__ r, int n) {
  int i = blockIdx.x * 256 + threadIdx.x;
  if (i < n) r[i] = 1.0f / fmaxf((float)(ptr[i + 1] - ptr[i]), 1.0f);
}

// ---------------- dense GEMM: C[Mx128] = act( rowmul(reluA(A)) @ W ) ----------------
template<bool OBF>
__global__ __launch_bounds__(256)
void k_gemm128(int M, const float* __restrict__ A, int K,
               const float* __restrict__ W, const float* __restrict__ dgA,
               int reluA, int act, void* __restrict__ C)
{
  __shared__ float sA[32][132];
  __shared__ float sW[32][132];
  const int t = threadIdx.x, tr = t >> 4, tc = t & 15;
  const int row0 = blockIdx.x * 128;
  float acc[8][8];
  #pragma unroll
  for (int i = 0; i < 8; ++i)
    #pragma unroll
    for (int j = 0; j < 8; ++j) acc[i][j] = 0.f;

  #pragma unroll 1
  for (int k0 = 0; k0 < K; k0 += 32) {
    __syncthreads();
    #pragma unroll
    for (int j = 0; j < 4; ++j) {
      int idx = t * 4 + j * 1024;
      int r = idx >> 5, kk = idx & 31;
      int gr = row0 + r; if (gr > M - 1) gr = M - 1;
      float4 va = *(const float4*)(A + (size_t)gr * K + k0 + kk);
      if (reluA) {
        va.x = fmaxf(va.x, 0.f); va.y = fmaxf(va.y, 0.f);
        va.z = fmaxf(va.z, 0.f); va.w = fmaxf(va.w, 0.f);
      }
      if (dgA) {
        float sc = dgA[gr];
        va.x *= sc; va.y *= sc; va.z *= sc; va.w *= sc;
      }
      sA[kk + 0][r] = va.x; sA[kk + 1][r] = va.y;
      sA[kk + 2][r] = va.z; sA[kk + 3][r] = va.w;
    }
    #pragma unroll
    for (int j = 0; j < 4; ++j) {
      int idx = t * 4 + j * 1024;
      int kk = idx >> 7, c = idx & 127;
      *(float4*)&sW[kk][c] = *(const float4*)(W + (size_t)(k0 + kk) * 128 + c);
    }
    __syncthreads();
    #pragma unroll
    for (int kk = 0; kk < 32; ++kk) {
      float a[8], w[8];
      *(float4*)&a[0] = *(const float4*)&sA[kk][tr * 8];
      *(float4*)&a[4] = *(const float4*)&sA[kk][tr * 8 + 4];
      *(float4*)&w[0] = *(const float4*)&sW[kk][tc * 8];
      *(float4*)&w[4] = *(const float4*)&sW[kk][tc * 8 + 4];
      #pragma unroll
      for (int i = 0; i < 8; ++i)
        #pragma unroll
        for (int j = 0; j < 8; ++j)
          acc[i][j] = fmaf(a[i], w[j], acc[i][j]);
    }
  }
  #pragma unroll 1
  for (int i = 0; i < 8; ++i) {
    int gr = row0 + tr * 8 + i;
    if (gr >= M) return;
    float o[8];
    #pragma unroll
    for (int j = 0; j < 8; ++j) {
      float vv = acc[i][j];
      if (act == 1)      vv = fmaxf(vv, 0.f);
      else if (act == 2) vv = vv > 0.f ? vv : vv * 0.2f;
      o[j] = vv;
    }
    if (OBF) {
      unsigned int pk[4];
      #pragma unroll
      for (int q = 0; q < 4; ++q)
        pk[q] = f2bf(o[2 * q]) | (f2bf(o[2 * q + 1]) << 16);
      uint4 st = {pk[0], pk[1], pk[2], pk[3]};
      *(uint4*)((unsigned short*)C + (size_t)gr * 128 + tc * 8) = st;
    } else {
      float* p = (float*)C + (size_t)gr * 128 + tc * 8;
      *(float4*)p       = *(const float4*)&o[0];
      *(float4*)(p + 4) = *(const float4*)&o[4];
    }
  }
}

// ---------------- gather-GEMM: OUT[seg] (+)= [segment-gather-sum rows] @ W ----------------
template<int K, int SPB, bool SBF, bool OBF>
__global__ __launch_bounds__(256)
void k_gg(int nseg, const int* __restrict__ rp, const int* __restrict__ ent,
          const float* __restrict__ entw, int segscale, int reluA,
          const void* __restrict__ SRC, const float* __restrict__ W,
          void* __restrict__ OUT, int beta)
{
  constexpr int RPT = SPB / 16;
  __shared__ float sA[K][SPB + 4];
  __shared__ float sW[32][132];
  const int t = threadIdx.x, wv = t >> 6, lane = t & 63;
  const int tr = t >> 4, tc = t & 15;
  const int seg0 = blockIdx.x * SPB;

  // ---- gather phase: wave-uniform segments, coalesced row loads ----
  #pragma unroll 1
  for (int i = 0; i < SPB / 4; ++i) {
    int col = wv + 4 * i;
    int seg = seg0 + col;
    float a0 = 0.f, a1 = 0.f;
    if (seg < nseg) {
      int p0 = rp[seg], p1 = rp[seg + 1];
      int j = p0;
      for (; j + 1 < p1; j += 2) {          // 2-unrolled for MLP
        int s0 = ent[j], s1 = ent[j + 1];
        float w0 = entw ? entw[j] : 1.f;
        float w1 = entw ? entw[j + 1] : 1.f;
        float x0, x1, y0, y1;
        if constexpr (SBF) {
          unsigned int u0 = *(const unsigned int*)((const unsigned short*)SRC + (size_t)s0 * K + 2 * lane);
          unsigned int u1 = *(const unsigned int*)((const unsigned short*)SRC + (size_t)s1 * K + 2 * lane);
          x0 = bf2f(u0 & 0xffffu); x1 = bf2f(u0 >> 16);
          y0 = bf2f(u1 & 0xffffu); y1 = bf2f(u1 >> 16);
        } else if constexpr (K == 64) {
          x0 = ((const float*)SRC)[(size_t)s0 * K + lane]; x1 = 0.f;
          y0 = ((const float*)SRC)[(size_t)s1 * K + lane]; y1 = 0.f;
        } else {
          float2 r0 = ((const float2*)((const float*)SRC + (size_t)s0 * K))[lane];
          float2 r1 = ((const float2*)((const float*)SRC + (size_t)s1 * K))[lane];
          x0 = r0.x; x1 = r0.y; y0 = r1.x; y1 = r1.y;
        }
        if (reluA) {
          x0 = fmaxf(x0, 0.f); x1 = fmaxf(x1, 0.f);
          y0 = fmaxf(y0, 0.f); y1 = fmaxf(y1, 0.f);
        }
        a0 = fmaf(w0, x0, a0); a1 = fmaf(w0, x1, a1);
        a0 = fmaf(w1, y0, a0); a1 = fmaf(w1, y1, a1);
      }
      if (j < p1) {
        int s0 = ent[j];
        float w0 = entw ? entw[j] : 1.f;
        float x0, x1;
        if constexpr (SBF) {
          unsigned int u0 = *(const unsigned int*)((const unsigned short*)SRC + (size_t)s0 * K + 2 * lane);
          x0 = bf2f(u0 & 0xffffu); x1 = bf2f(u0 >> 16);
        } else if constexpr (K == 64) {
          x0 = ((const float*)SRC)[(size_t)s0 * K + lane]; x1 = 0.f;
        } else {
          float2 r0 = ((const float2*)((const float*)SRC + (size_t)s0 * K))[lane];
          x0 = r0.x; x1 = r0.y;
        }
        if (reluA) { x0 = fmaxf(x0, 0.f); x1 = fmaxf(x1, 0.f); }
        a0 = fmaf(w0, x0, a0); a1 = fmaf(w0, x1, a1);
      }
      if (segscale) {
        float sc = 1.f / fmaxf((float)(p1 - p0), 1.f);
        a0 *= sc; a1 *= sc;
      }
    }
    if constexpr (K == 64) {
      sA[lane][col] = a0;
    } else {
      sA[2 * lane][col] = a0;
      sA[2 * lane + 1][col] = a1;
    }
  }
  __syncthreads();

  // ---- GEMM phase ----
  float acc[RPT][8];
  #pragma unroll
  for (int i = 0; i < RPT; ++i)
    #pragma unroll
    for (int j = 0; j < 8; ++j) acc[i][j] = 0.f;

  #pragma unroll 1
  for (int k0 = 0; k0 < K; k0 += 32) {
    #pragma unroll
    for (int j = 0; j < 4; ++j) {
      int idx = t * 4 + j * 1024;
      int kk = idx >> 7, c = idx & 127;
      *(float4*)&sW[kk][c] = *(const float4*)(W + (size_t)(k0 + kk) * 128 + c);
    }
    __syncthreads();
    #pragma unroll
    for (int kk = 0; kk < 32; ++kk) {
      float a[RPT], w8[8];
      if constexpr (RPT == 8) {
        *(float4*)&a[0] = *(const float4*)&sA[k0 + kk][tr * 8];
        *(float4*)&a[4] = *(const float4*)&sA[k0 + kk][tr * 8 + 4];
      } else {
        *(float2*)&a[0] = *(const float2*)&sA[k0 + kk][tr * 2];
      }
      *(float4*)&w8[0] = *(const float4*)&sW[kk][tc * 8];
      *(float4*)&w8[4] = *(const float4*)&sW[kk][tc * 8 + 4];
      #pragma unroll
      for (int i = 0; i < RPT; ++i)
        #pragma unroll
        for (int j = 0; j < 8; ++j)
          acc[i][j] = fmaf(a[i], w8[j], acc[i][j]);
    }
    __syncthreads();
  }

  // ---- epilogue: exclusive row ownership, plain RMW (no atomics) ----
  #pragma unroll 1
  for (int i = 0; i < RPT; ++i) {
    int seg = seg0 + tr * RPT + i;
    if (seg >= nseg) continue;
    float o[8];
    #pragma unroll
    for (int j = 0; j < 8; ++j) o[j] = acc[i][j];
    if constexpr (OBF) {
      unsigned short* p = (unsigned short*)OUT + (size_t)seg * 128 + tc * 8;
      if (beta) {
        uint4 u = *(const uint4*)p;
        unsigned int uu[4] = {u.x, u.y, u.z, u.w};
        #pragma unroll
        for (int q = 0; q < 4; ++q) {
          o[2 * q]     += bf2f(uu[q] & 0xffffu);
          o[2 * q + 1] += bf2f(uu[q] >> 16);
        }
      }
      unsigned int pk[4];
      #pragma unroll
      for (int q = 0; q < 4; ++q)
        pk[q] = f2bf(o[2 * q]) | (f2bf(o[2 * q + 1]) << 16);
      uint4 st = {pk[0], pk[1], pk[2], pk[3]};
      *(uint4*)p = st;
    } else {
      float* p = (float*)OUT + (size_t)seg * 128 + tc * 8;
      if (beta) {
        float4 c0 = *(const float4*)p, c1 = *(const float4*)(p + 4);
        o[0] += c0.x; o[1] += c0.y; o[2] += c0.z; o[3] += c0.w;
        o[4] += c1.x; o[5] += c1.y; o[6] += c1.z; o[7] += c1.w;
      }
      *(float4*)p       = *(const float4*)&o[0];
      *(float4*)(p + 4) = *(const float4*)&o[4];
    }
  }
}

// ---------------- gather segment-mean (128-wide), O[seg] += mean ----------------
__global__ __launch_bounds__(256)
void k_gsum(const int* __restrict__ rp, const int* __restrict__ ent,
            const float* __restrict__ SRC, float* __restrict__ O, int nseg)
{
  int wv = threadIdx.x >> 6, lane = threadIdx.x & 63;
  int seg = blockIdx.x * 4 + wv;
  if (seg >= nseg) return;
  int p0 = rp[seg], p1 = rp[seg + 1];
  if (p0 >= p1) return;
  float a0 = 0.f, a1 = 0.f;
  int j = p0;
  for (; j + 1 < p1; j += 2) {
    int s0 = ent[j], s1 = ent[j + 1];
    float2 v0 = ((const float2*)(SRC + (size_t)s0 * 128))[lane];
    float2 v1 = ((const float2*)(SRC + (size_t)s1 * 128))[lane];
    a0 += v0.x + v1.x; a1 += v0.y + v1.y;
  }
  if (j < p1) {
    float2 v0 = ((const float2*)(SRC + (size_t)ent[j] * 128))[lane];
    a0 += v0.x; a1 += v0.y;
  }
  float sc = 1.f / fmaxf((float)(p1 - p0), 1.f);
  float2* orow = (float2*)(O + (size_t)seg * 128);
  float2 cur = orow[lane];
  cur.x += a0 * sc; cur.y += a1 * sc;
  orow[lane] = cur;
}

// ---------------- fused attention: online softmax + PV, one wave per node ----------------
__global__ __launch_bounds__(256)
void k_attn(const int* __restrict__ rp, const int* __restrict__ ent,
            const float* __restrict__ q, const float* __restrict__ kb,
            const float* __restrict__ vb, float* __restrict__ o, int nseg)
{
  int wv = threadIdx.x >> 6, lane = threadIdx.x & 63;
  int seg = blockIdx.x * 4 + wv;
  if (seg >= nseg) return;
  int p0 = rp[seg], p1 = rp[seg + 1];
  if (p0 >= p1) return;
  float2 q2 = ((const float2*)(q + (size_t)seg * 128))[lane];
  float m = -1e30f, l = 0.f, o0 = 0.f, o1 = 0.f;
  for (int j = p0; j < p1; ++j) {
    int s = ent[j];
    float2 k2 = ((const float2*)(kb + (size_t)s * 128))[lane];
    float d = fmaf(q2.x, k2.x, q2.y * k2.y);
    #pragma unroll
    for (int off = 1; off < 64; off <<= 1) d += __shfl_xor(d, off);
    float sc = d * 0.088388347648318447f;          // 1/sqrt(128)
    sc = sc > 0.f ? sc : 0.2f * sc;                // leaky 0.2
    float mn = fmaxf(m, sc);
    float scale = expf(m - mn);
    float e = expf(sc - mn);
    float2 v2 = ((const float2*)(vb + (size_t)s * 128))[lane];
    l  = l * scale + e;
    o0 = o0 * scale + e * v2.x;
    o1 = o1 * scale + e * v2.y;
    m = mn;
  }
  float inv = 1.f / fmaxf(l, 1e-9f);
  float2* orow = (float2*)(o + (size_t)seg * 128);
  float2 cur = orow[lane];
  cur.x += o0 * inv; cur.y += o1 * inv;
  orow[lane] = cur;
}

// ---------------- classifier + log_softmax ----------------
__global__ __launch_bounds__(256)
void k_out(const float* __restrict__ attn, const float* __restrict__ Wout,
           float* __restrict__ out, int n) {
  __shared__ float sW[128 * 64];
  for (int i = threadIdx.x; i < 128 * 64; i += 256) sW[i] = Wout[i];
  __syncthreads();
  int wave = threadIdx.x >> 6, lane = threadIdx.x & 63;
  int row = blockIdx.x * 4 + wave;
  if (row >= n) return;
  const float* a = attn + (size_t)row * 128;
  float z = 0.f;
  #pragma unroll 8
  for (int k = 0; k < 128; ++k) z = fmaf(a[k], sW[k * 64 + lane], z);
  float mx = z;
  #pragma unroll
  for (int off = 32; off; off >>= 1) mx = fmaxf(mx, __shfl_xor(mx, off));
  float ee = expf(z - mx);
  float ss = ee;
  #pragma unroll
  for (int off = 32; off; off >>= 1) ss += __shfl_xor(ss, off);
  out[(size_t)row * 64 + lane] = z - mx - logf(ss);
}

extern "C" void kernel_launch(void* const* d_in, const int* in_sizes, int n_in,
                              void* d_out, int out_size, void* d_ws, size_t ws_size,
                              hipStream_t stream) {
  (void)in_sizes; (void)n_in; (void)out_size;
  const float* x        = (const float*)d_in[0];
  const float* et       = (const float*)d_in[1];
  const int*   H0       = (const int*)d_in[2];
  const int*   H1       = H0 + Ee;
  const int*   src      = (const int*)d_in[3];
  const int*   dst      = src + Ee;
  const int*   src_lg   = (const int*)d_in[4];
  const int*   dst_lg   = src_lg + LGEe;
  const float* W_tsa1_s = (const float*)d_in[5];
  const float* W_tsa1_n = (const float*)d_in[6];
  const float* W_tsa2_s = (const float*)d_in[7];
  const float* W_tsa2_n = (const float*)d_in[8];
  const float* W_etn    = (const float*)d_in[9];
  const float* W_eg_lin = (const float*)d_in[10];
  const float* W_ea_s   = (const float*)d_in[11];
  const float* W_ea_n   = (const float*)d_in[12];
  const float* W_an1_s  = (const float*)d_in[13];
  const float* W_an1_n  = (const float*)d_in[14];
  const float* W_an2_s  = (const float*)d_in[15];
  const float* W_an2_n  = (const float*)d_in[16];
  const float* Wq       = (const float*)d_in[17];
  const float* Wk       = (const float*)d_in[18];
  const float* Wv       = (const float*)d_in[19];
  const float* W_out    = (const float*)d_in[20];
  float* out = (float*)d_out;

  // ---- workspace carve (~281 MB peak) ----
  char* wp = (char*)d_ws;
  size_t avail = ws_size;
  auto alloc = [&](size_t bytes) -> void* {
    void* r = (void*)wp;
    size_t pad = (bytes + 255) & ~(size_t)255;
    wp += pad; avail = (avail >= pad) ? avail - pad : 0;
    return r;
  };
  const size_t NH = (size_t)Nn * 128;
  unsigned short* BUF = (unsigned short*)alloc((size_t)Ee * 128 * 2); // 204.8MB bf16 h1
  float* agg   = (float*)alloc(NH * 4);
  int* ptrA  = (int*)alloc(((size_t)Ee + 1) * 4);
  int* cntA  = (int*)alloc((size_t)Ee * 4);
  int* entA  = (int*)alloc((size_t)LGEe * 4);
  int* ptrB  = (int*)alloc(((size_t)Nn + 1) * 4);
  int* cntB  = (int*)alloc((size_t)Nn * 4);
  int* entBs = (int*)alloc((size_t)2 * LGEe * 4);
  float* entBw = (float*)alloc((size_t)2 * LGEe * 4);
  int* ptrC  = (int*)alloc(((size_t)Nn + 1) * 4);
  int* cntC  = (int*)alloc((size_t)Nn * 4);
  int* entC  = (int*)alloc((size_t)2 * Ee * 4);
  int* ptrD  = (int*)alloc(((size_t)Nn + 1) * 4);
  int* cntD  = (int*)alloc((size_t)Nn * 4);
  int* entD  = (int*)alloc((size_t)Ee * 4);
  float* rdegN = (float*)alloc((size_t)Nn * 4);
  int* bsum  = (int*)alloc(2048 * 4);
  if (avail == 0 && wp > (char*)d_ws + ws_size) return;  // ws too small: clean fail

  // node-phase f32 arrays overlay BUF (dead after agg is built): 8 x 25.6MB = 204.8MB
  float* er  = (float*)BUF + 0 * NH;
  float* ae  = (float*)BUF + 1 * NH;
  float* hn  = (float*)BUF + 2 * NH;
  float* hn2 = (float*)BUF + 3 * NH;
  float* qb  = (float*)BUF + 4 * NH;
  float* kb  = (float*)BUF + 5 * NH;
  float* vb  = (float*)BUF + 6 * NH;
  float* tmp = (float*)BUF + 7 * NH;

  auto cdiv = [](long a, long b) { return (int)((a + b - 1) / b); };
  auto scan = [&](int* cnt, int* ptr, int n, int total) {
    int nb = cdiv(n, 1024);
    k_scan1<<<nb, 256, 0, stream>>>(cnt, ptr, bsum, n);
    k_scan2<<<1, 1024, 0, stream>>>(bsum, nb);
    k_scan3<<<cdiv(n, 256), 256, 0, stream>>>(ptr, bsum, n, total);
  };

  const int gLG = cdiv(LGEe, 256), gEe = cdiv(Ee, 256);

  // ---- CSR A: line-graph by dst_lg (E segments) ----
  hipMemsetAsync(cntA, 0, (size_t)Ee * 4, stream);
  k_count_direct<<<gLG, 256, 0, stream>>>(dst_lg, cntA, LGEe);
  scan(cntA, ptrA, Ee, LGEe);
  hipMemsetAsync(cntA, 0, (size_t)Ee * 4, stream);
  k_fillA<<<gLG, 256, 0, stream>>>(dst_lg, src_lg, ptrA, cntA, entA, LGEe);

  // ---- CSR B: composed H[b][dst_lg[m]] (N segments, 2*LGE entries) ----
  hipMemsetAsync(cntB, 0, (size_t)Nn * 4, stream);
  k_count_comp<<<gLG, 256, 0, stream>>>(H0, dst_lg, cntB, LGEe);
  k_count_comp<<<gLG, 256, 0, stream>>>(H1, dst_lg, cntB, LGEe);
  scan(cntB, ptrB, Nn, 2 * LGEe);
  hipMemsetAsync(cntB, 0, (size_t)Nn * 4, stream);
  k_fillB<<<gLG, 256, 0, stream>>>(H0, dst_lg, src_lg, ptrA, ptrB, cntB, entBs, entBw, LGEe);
  k_fillB<<<gLG, 256, 0, stream>>>(H1, dst_lg, src_lg, ptrA, ptrB, cntB, entBs, entBw, LGEe);

  // ---- CSR C: H incidence (N segments, 2*E entries, value = edge id) ----
  hipMemsetAsync(cntC, 0, (size_t)Nn * 4, stream);
  k_count_direct<<<gEe, 256, 0, stream>>>(H0, cntC, Ee);
  k_count_direct<<<gEe, 256, 0, stream>>>(H1, cntC, Ee);
  scan(cntC, ptrC, Nn, 2 * Ee);
  hipMemsetAsync(cntC, 0, (size_t)Nn * 4, stream);
  k_fillC<<<gEe, 256, 0, stream>>>(H0, ptrC, cntC, entC, Ee);
  k_fillC<<<gEe, 256, 0, stream>>>(H1, ptrC, cntC, entC, Ee);

  // ---- CSR D: raw graph by dst (N segments, E entries, value = src) ----
  hipMemsetAsync(cntD, 0, (size_t)Nn * 4, stream);
  k_count_direct<<<gEe, 256, 0, stream>>>(dst, cntD, Ee);
  scan(cntD, ptrD, Nn, Ee);
  hipMemsetAsync(cntD, 0, (size_t)Nn * 4, stream);
  k_fillD<<<gEe, 256, 0, stream>>>(dst, src, ptrD, cntD, entD, Ee);
  k_rdeg<<<cdiv(Nn, 256), 256, 0, stream>>>(ptrC, rdegN, Nn);

  const int gE128 = Ee / 128;           // 6250
  const int gN128 = cdiv(Nn, 128);      // 391
  const int gN32  = cdiv(Nn, 32);       // 1563
  const int gW    = cdiv(Nn, 4);        // 12500

  // ---- TSA layer 1 (h1, bf16, PRE-relu) ----
  k_gemm128<true><<<gE128, 256, 0, stream>>>(Ee, et, 64, W_tsa1_s, nullptr, 0, 0, BUF);
  k_gg<64, 128, false, true><<<gE128, 256, 0, stream>>>(
      Ee, ptrA, entA, nullptr, 1, 0, et, W_tsa1_n, BUF, 1);

  // ---- TSA layer 2 + EdgeToNode fused at N-scale (agg = P@W2s + Q@W2n) ----
  k_gg<128, 32, true, false><<<gN32, 256, 0, stream>>>(
      Nn, ptrC, entC, nullptr, 0, 1, BUF, W_tsa2_s, agg, 0);
  k_gg<128, 32, true, false><<<gN32, 256, 0, stream>>>(
      Nn, ptrB, entBs, entBw, 0, 1, BUF, W_tsa2_n, agg, 1);
  k_gemm128<false><<<gN128, 256, 0, stream>>>(Nn, agg, 128, W_etn, rdegN, 0, 2, tmp);
  k_gemm128<false><<<gN128, 256, 0, stream>>>(Nn, tmp, 128, W_eg_lin, nullptr, 0, 0, er);

  // ---- edge_aggr SAGE ----
  k_gemm128<false><<<gN128, 256, 0, stream>>>(Nn, er, 128, W_ea_s, nullptr, 0, 0, ae);
  k_gemm128<false><<<gN128, 256, 0, stream>>>(Nn, er, 128, W_ea_n, nullptr, 0, 0, tmp);
  k_gsum<<<gW, 256, 0, stream>>>(ptrD, entD, tmp, ae, Nn);

  // ---- attr_node_model (hn kept pre-relu; relu applied on read) ----
  k_gemm128<false><<<gN128, 256, 0, stream>>>(Nn, x, 256, W_an1_s, nullptr, 0, 0, hn);
  k_gemm128<false><<<gN128, 256, 0, stream>>>(Nn, x, 256, W_an1_n, nullptr, 0, 0, tmp);
  k_gsum<<<gW, 256, 0, stream>>>(ptrD, entD, tmp, hn, Nn);
  k_gemm128<false><<<gN128, 256, 0, stream>>>(Nn, hn, 128, W_an2_s, nullptr, 1, 0, hn2);
  k_gemm128<false><<<gN128, 256, 0, stream>>>(Nn, hn, 128, W_an2_n, nullptr, 1, 0, tmp);
  k_gsum<<<gW, 256, 0, stream>>>(ptrD, entD, tmp, hn2, Nn);

  // ---- MixAttention (fused online softmax; out accumulated into hn2) ----
  k_gemm128<false><<<gN128, 256, 0, stream>>>(Nn, hn2, 128, Wq, nullptr, 0, 0, qb);
  k_gemm128<false><<<gN128, 256, 0, stream>>>(Nn, ae, 128, Wk, nullptr, 0, 0, kb);
  k_gemm128<false><<<gN128, 256, 0, stream>>>(Nn, ae, 128, Wv, nullptr, 0, 0, vb);
  k_attn<<<gW, 256, 0, stream>>>(ptrD, entD, qb, kb, vb, hn2, Nn);

  // ---- classifier + log_softmax ----
  k_out<<<gW, 256, 0, stream>>>(hn2, W_out, out, Nn);
}

// Round 4
// 3696.521 us; speedup vs baseline: 7.0997x; 1.2456x over previous
//
#include <hip/hip_runtime.h>
#include <cstddef>

static constexpr int Nn   = 50000;
static constexpr int Ee   = 800000;
static constexpr int LGEe = 1600000;

__device__ __forceinline__ float bf2f(unsigned int u16) {
  return __uint_as_float(u16 << 16);
}
__device__ __forceinline__ unsigned int f2bf(float f) {
  unsigned int u = __float_as_uint(f);
  u += 0x7fffu + ((u >> 16) & 1u);   // RNE
  return u >> 16;
}

// ---------------- CSR build kernels ----------------
__global__ __launch_bounds__(256)
void k_count_direct(const int* __restrict__ idx, int* __restrict__ cnt, int n) {
  int i = blockIdx.x * 256 + threadIdx.x;
  if (i < n) atomicAdd(&cnt[idx[i]], 1);
}
__global__ __launch_bounds__(256)
void k_count_comp(const int* __restrict__ Hrow, const int* __restrict__ dlg,
                  int* __restrict__ cnt, int n) {
  int i = blockIdx.x * 256 + threadIdx.x;
  if (i < n) atomicAdd(&cnt[Hrow[dlg[i]]], 1);
}
__global__ __launch_bounds__(256)
void k_scan1(const int* __restrict__ in, int* __restrict__ out,
             int* __restrict__ bsum, int n) {
  __shared__ int sd[256];
  int tid = threadIdx.x;
  int base = blockIdx.x * 1024 + tid * 4;
  int4 v = {0, 0, 0, 0};
  if (base < n) v = *(const int4*)(in + base);   // n % 4 == 0 for all uses
  int s = v.x + v.y + v.z + v.w;
  sd[tid] = s; __syncthreads();
  for (int off = 1; off < 256; off <<= 1) {
    int t_ = (tid >= off) ? sd[tid - off] : 0; __syncthreads();
    sd[tid] += t_; __syncthreads();
  }
  int excl = sd[tid] - s;
  if (base < n) {
    int4 o; o.x = excl; o.y = o.x + v.x; o.z = o.y + v.y; o.w = o.z + v.z;
    *(int4*)(out + base) = o;
  }
  if (tid == 255) bsum[blockIdx.x] = sd[255];
}
__global__ __launch_bounds__(1024)
void k_scan2(int* __restrict__ b, int nb) {
  __shared__ int sd[1024];
  int tid = threadIdx.x;
  int v = (tid < nb) ? b[tid] : 0;
  sd[tid] = v; __syncthreads();
  for (int off = 1; off < 1024; off <<= 1) {
    int t_ = (tid >= off) ? sd[tid - off] : 0; __syncthreads();
    sd[tid] += t_; __syncthreads();
  }
  if (tid < nb) b[tid] = sd[tid] - v;
}
__global__ __launch_bounds__(256)
void k_scan3(int* __restrict__ out, const int* __restrict__ bsum, int n, int total) {
  int i = blockIdx.x * 256 + threadIdx.x;
  if (i < n) out[i] += bsum[i >> 10];
  if (i == 0) out[n] = total;
}
__global__ __launch_bounds__(256)
void k_fillA(const int* __restrict__ dlg, const int* __restrict__ slg,
             const int* __restrict__ ptr, int* __restrict__ cur,
             int* __restrict__ ent, int n) {
  int m = blockIdx.x * 256 + threadIdx.x;
  if (m >= n) return;
  int d = dlg[m];
  int pos = ptr[d] + atomicAdd(&cur[d], 1);
  ent[pos] = slg[m];
}
__global__ __launch_bounds__(256)
void k_fillB(const int* __restrict__ Hrow, const int* __restrict__ dlg,
             const int* __restrict__ slg, const int* __restrict__ ptrA,
             const int* __restrict__ ptrB, int* __restrict__ cur,
             int* __restrict__ entS, float* __restrict__ entW, int n) {
  int m = blockIdx.x * 256 + threadIdx.x;
  if (m >= n) return;
  int d = dlg[m];
  int seg = Hrow[d];
  int pos = ptrB[seg] + atomicAdd(&cur[seg], 1);
  entS[pos] = slg[m];
  int la = ptrA[d + 1] - ptrA[d];
  entW[pos] = 1.0f / (float)max(la, 1);
}
__global__ __launch_bounds__(256)
void k_fillC(const int* __restrict__ Hrow, const int* __restrict__ ptr,
             int* __restrict__ cur, int* __restrict__ ent, int n) {
  int e = blockIdx.x * 256 + threadIdx.x;
  if (e >= n) return;
  int seg = Hrow[e];
  int pos = ptr[seg] + atomicAdd(&cur[seg], 1);
  ent[pos] = e;
}
__global__ __launch_bounds__(256)
void k_fillD(const int* __restrict__ dstA, const int* __restrict__ srcA,
             const int* __restrict__ ptr, int* __restrict__ cur,
             int* __restrict__ ent, int n) {
  int e = blockIdx.x * 256 + threadIdx.x;
  if (e >= n) return;
  int seg = dstA[e];
  int pos = ptr[seg] + atomicAdd(&cur[seg], 1);
  ent[pos] = srcA[e];
}
__global__ __launch_bounds__(256)
void k_rdeg(const int* __restrict__ ptr, float* __restrict__ r, int n) {
  int i = blockIdx.x * 256 + threadIdx.x;
  if (i < n) r[i] = 1.0f / fmaxf((float)(ptr[i + 1] - ptr[i]), 1.0f);
}

// ---------------- dense GEMM: C[Mx128] = act( rowmul(reluA(A)) @ W ) ----------------
__global__ __launch_bounds__(256)
void k_gemm128(int M, const float* __restrict__ A, int K,
               const float* __restrict__ W, const float* __restrict__ dgA,
               int reluA, int act, float* __restrict__ C)
{
  __shared__ float sA[32][132];
  __shared__ float sW[32][132];
  const int t = threadIdx.x, tr = t >> 4, tc = t & 15;
  const int row0 = blockIdx.x * 128;
  float acc[8][8];
  #pragma unroll
  for (int i = 0; i < 8; ++i)
    #pragma unroll
    for (int j = 0; j < 8; ++j) acc[i][j] = 0.f;

  #pragma unroll 1
  for (int k0 = 0; k0 < K; k0 += 32) {
    __syncthreads();
    #pragma unroll
    for (int j = 0; j < 4; ++j) {
      int idx = t * 4 + j * 1024;
      int r = idx >> 5, kk = idx & 31;
      int gr = row0 + r; if (gr > M - 1) gr = M - 1;
      float4 va = *(const float4*)(A + (size_t)gr * K + k0 + kk);
      if (reluA) {
        va.x = fmaxf(va.x, 0.f); va.y = fmaxf(va.y, 0.f);
        va.z = fmaxf(va.z, 0.f); va.w = fmaxf(va.w, 0.f);
      }
      if (dgA) {
        float sc = dgA[gr];
        va.x *= sc; va.y *= sc; va.z *= sc; va.w *= sc;
      }
      sA[kk + 0][r] = va.x; sA[kk + 1][r] = va.y;
      sA[kk + 2][r] = va.z; sA[kk + 3][r] = va.w;
    }
    #pragma unroll
    for (int j = 0; j < 4; ++j) {
      int idx = t * 4 + j * 1024;
      int kk = idx >> 7, c = idx & 127;
      *(float4*)&sW[kk][c] = *(const float4*)(W + (size_t)(k0 + kk) * 128 + c);
    }
    __syncthreads();
    #pragma unroll
    for (int kk = 0; kk < 32; ++kk) {
      float a[8], w[8];
      *(float4*)&a[0] = *(const float4*)&sA[kk][tr * 8];
      *(float4*)&a[4] = *(const float4*)&sA[kk][tr * 8 + 4];
      *(float4*)&w[0] = *(const float4*)&sW[kk][tc * 8];
      *(float4*)&w[4] = *(const float4*)&sW[kk][tc * 8 + 4];
      #pragma unroll
      for (int i = 0; i < 8; ++i)
        #pragma unroll
        for (int j = 0; j < 8; ++j)
          acc[i][j] = fmaf(a[i], w[j], acc[i][j]);
    }
  }
  #pragma unroll 1
  for (int i = 0; i < 8; ++i) {
    int gr = row0 + tr * 8 + i;
    if (gr >= M) return;
    float o[8];
    #pragma unroll
    for (int j = 0; j < 8; ++j) {
      float vv = acc[i][j];
      if (act == 1)      vv = fmaxf(vv, 0.f);
      else if (act == 2) vv = vv > 0.f ? vv : vv * 0.2f;
      o[j] = vv;
    }
    float* p = C + (size_t)gr * 128 + tc * 8;
    *(float4*)p       = *(const float4*)&o[0];
    *(float4*)(p + 4) = *(const float4*)&o[4];
  }
}

// ---------------- fused TSA1: BUF[e] = bf16( et[e]@Ws + mean_{s in A(e)} et[s] @ Wn ) ----
// 64 segs/block, K = 128 = [direct 64 | gathered 64]. Single pass, no RMW.
__global__ __launch_bounds__(256)
void k_tsa1(const float* __restrict__ et,
            const int* __restrict__ rp, const int* __restrict__ ent,
            const float* __restrict__ Ws, const float* __restrict__ Wn,
            unsigned short* __restrict__ BUF)
{
  __shared__ float sA[128][68];   // 34816 B
  __shared__ float sW[32][132];   // 16896 B  -> 51712 total, 3 blocks/CU
  const int t = threadIdx.x, wv = t >> 6, lane = t & 63;
  const int tr = t >> 4, tc = t & 15;
  const int seg0 = blockIdx.x * 64;
  const int segbase = seg0 + wv * 16;

  // shfl-preload row pointers: lanes 0..16 hold rp[segbase+lane]
  int rpv = (lane <= 16) ? rp[segbase + lane] : 0;

  #pragma unroll 1
  for (int i = 0; i < 16; ++i) {
    int col = wv * 16 + i;
    int seg = seg0 + col;                     // always < Ee (Ee % 64 == 0)
    // direct half
    sA[lane][col] = et[(size_t)seg * 64 + lane];
    // gathered half
    int p0 = __shfl(rpv, i), p1 = __shfl(rpv, i + 1);
    float a = 0.f;
    int j = p0;
    for (; j + 3 < p1; j += 4) {
      int s0 = ent[j], s1 = ent[j + 1], s2 = ent[j + 2], s3 = ent[j + 3];
      float x0 = et[(size_t)s0 * 64 + lane];
      float x1 = et[(size_t)s1 * 64 + lane];
      float x2 = et[(size_t)s2 * 64 + lane];
      float x3 = et[(size_t)s3 * 64 + lane];
      a += (x0 + x1) + (x2 + x3);
    }
    for (; j < p1; ++j) a += et[(size_t)ent[j] * 64 + lane];
    a *= 1.f / fmaxf((float)(p1 - p0), 1.f);
    sA[64 + lane][col] = a;
  }
  __syncthreads();

  float acc[4][8];
  #pragma unroll
  for (int i = 0; i < 4; ++i)
    #pragma unroll
    for (int j = 0; j < 8; ++j) acc[i][j] = 0.f;

  #pragma unroll 1
  for (int k0 = 0; k0 < 128; k0 += 32) {
    const float* Wsrc = (k0 < 64) ? (Ws + (size_t)k0 * 128)
                                  : (Wn + (size_t)(k0 - 64) * 128);
    #pragma unroll
    for (int j = 0; j < 4; ++j) {
      int idx = t * 4 + j * 1024;
      int kk = idx >> 7, c = idx & 127;
      *(float4*)&sW[kk][c] = *(const float4*)(Wsrc + (size_t)kk * 128 + c);
    }
    __syncthreads();
    #pragma unroll
    for (int kk = 0; kk < 32; ++kk) {
      float a4[4], w8[8];
      *(float4*)&a4[0] = *(const float4*)&sA[k0 + kk][tr * 4];
      *(float4*)&w8[0] = *(const float4*)&sW[kk][tc * 8];
      *(float4*)&w8[4] = *(const float4*)&sW[kk][tc * 8 + 4];
      #pragma unroll
      for (int i = 0; i < 4; ++i)
        #pragma unroll
        for (int j = 0; j < 8; ++j)
          acc[i][j] = fmaf(a4[i], w8[j], acc[i][j]);
    }
    __syncthreads();
  }

  #pragma unroll
  for (int i = 0; i < 4; ++i) {
    int seg = seg0 + tr * 4 + i;
    unsigned int pk[4];
    #pragma unroll
    for (int q = 0; q < 4; ++q)
      pk[q] = f2bf(acc[i][2 * q]) | (f2bf(acc[i][2 * q + 1]) << 16);
    uint4 st = {pk[0], pk[1], pk[2], pk[3]};
    *(uint4*)(BUF + (size_t)seg * 128 + tc * 8) = st;
  }
}

// ---------------- gather-GEMM (bf16 src rows, K=128, relu-on-read): ----------------
// OUT[seg] (+)= [sum_{j in seg} w_j * relu(SRC[ent[j]])] @ W     (32 segs/block)
__global__ __launch_bounds__(256)
void k_gg2(int nseg, const int* __restrict__ rp, const int* __restrict__ ent,
           const float* __restrict__ entw, int segscale,
           const unsigned short* __restrict__ SRC, const float* __restrict__ W,
           float* __restrict__ OUT, int beta)
{
  __shared__ float sA[128][36];   // 18432 B
  __shared__ float sW[32][132];   // 16896 B -> 35328, 4 blocks/CU
  const int t = threadIdx.x, wv = t >> 6, lane = t & 63;
  const int tr = t >> 4, tc = t & 15;
  const int seg0 = blockIdx.x * 32;
  const int segbase = seg0 + wv * 8;
  int idxl = segbase + lane;
  int rpv = (lane <= 8 && idxl <= nseg) ? rp[idxl] : 0;

  #pragma unroll 1
  for (int i = 0; i < 8; ++i) {
    int col = wv * 8 + i;
    int seg = seg0 + col;
    float a0 = 0.f, a1 = 0.f;
    if (seg < nseg) {
      int p0 = __shfl(rpv, i), p1 = __shfl(rpv, i + 1);
      int j = p0;
      for (; j + 3 < p1; j += 4) {
        int s0 = ent[j], s1 = ent[j + 1], s2 = ent[j + 2], s3 = ent[j + 3];
        float w0 = entw ? entw[j] : 1.f,     w1 = entw ? entw[j + 1] : 1.f;
        float w2 = entw ? entw[j + 2] : 1.f, w3 = entw ? entw[j + 3] : 1.f;
        unsigned int u0 = *(const unsigned int*)(SRC + (size_t)s0 * 128 + 2 * lane);
        unsigned int u1 = *(const unsigned int*)(SRC + (size_t)s1 * 128 + 2 * lane);
        unsigned int u2 = *(const unsigned int*)(SRC + (size_t)s2 * 128 + 2 * lane);
        unsigned int u3 = *(const unsigned int*)(SRC + (size_t)s3 * 128 + 2 * lane);
        a0 = fmaf(w0, fmaxf(bf2f(u0 & 0xffffu), 0.f), a0);
        a1 = fmaf(w0, fmaxf(bf2f(u0 >> 16),     0.f), a1);
        a0 = fmaf(w1, fmaxf(bf2f(u1 & 0xffffu), 0.f), a0);
        a1 = fmaf(w1, fmaxf(bf2f(u1 >> 16),     0.f), a1);
        a0 = fmaf(w2, fmaxf(bf2f(u2 & 0xffffu), 0.f), a0);
        a1 = fmaf(w2, fmaxf(bf2f(u2 >> 16),     0.f), a1);
        a0 = fmaf(w3, fmaxf(bf2f(u3 & 0xffffu), 0.f), a0);
        a1 = fmaf(w3, fmaxf(bf2f(u3 >> 16),     0.f), a1);
      }
      for (; j < p1; ++j) {
        int s0 = ent[j];
        float w0 = entw ? entw[j] : 1.f;
        unsigned int u0 = *(const unsigned int*)(SRC + (size_t)s0 * 128 + 2 * lane);
        a0 = fmaf(w0, fmaxf(bf2f(u0 & 0xffffu), 0.f), a0);
        a1 = fmaf(w0, fmaxf(bf2f(u0 >> 16),     0.f), a1);
      }
      if (segscale) {
        float sc = 1.f / fmaxf((float)(p1 - p0), 1.f);
        a0 *= sc; a1 *= sc;
      }
    }
    sA[2 * lane][col]     = a0;
    sA[2 * lane + 1][col] = a1;
  }
  __syncthreads();

  float acc[2][8];
  #pragma unroll
  for (int i = 0; i < 2; ++i)
    #pragma unroll
    for (int j = 0; j < 8; ++j) acc[i][j] = 0.f;

  #pragma unroll 1
  for (int k0 = 0; k0 < 128; k0 += 32) {
    #pragma unroll
    for (int j = 0; j < 4; ++j) {
      int idx = t * 4 + j * 1024;
      int kk = idx >> 7, c = idx & 127;
      *(float4*)&sW[kk][c] = *(const float4*)(W + (size_t)(k0 + kk) * 128 + c);
    }
    __syncthreads();
    #pragma unroll
    for (int kk = 0; kk < 32; ++kk) {
      float a2[2], w8[8];
      *(float2*)&a2[0] = *(const float2*)&sA[k0 + kk][tr * 2];
      *(float4*)&w8[0] = *(const float4*)&sW[kk][tc * 8];
      *(float4*)&w8[4] = *(const float4*)&sW[kk][tc * 8 + 4];
      #pragma unroll
      for (int i = 0; i < 2; ++i)
        #pragma unroll
        for (int j = 0; j < 8; ++j)
          acc[i][j] = fmaf(a2[i], w8[j], acc[i][j]);
    }
    __syncthreads();
  }

  #pragma unroll
  for (int i = 0; i < 2; ++i) {
    int seg = seg0 + tr * 2 + i;
    if (seg >= nseg) continue;
    float o[8];
    #pragma unroll
    for (int j = 0; j < 8; ++j) o[j] = acc[i][j];
    float* p = OUT + (size_t)seg * 128 + tc * 8;
    if (beta) {
      float4 c0 = *(const float4*)p, c1 = *(const float4*)(p + 4);
      o[0] += c0.x; o[1] += c0.y; o[2] += c0.z; o[3] += c0.w;
      o[4] += c1.x; o[5] += c1.y; o[6] += c1.z; o[7] += c1.w;
    }
    *(float4*)p       = *(const float4*)&o[0];
    *(float4*)(p + 4) = *(const float4*)&o[4];
  }
}

// ---------------- gather segment-mean (128-wide), O[seg] += mean ----------------
__global__ __launch_bounds__(256)
void k_gsum(const int* __restrict__ rp, const int* __restrict__ ent,
            const float* __restrict__ SRC, float* __restrict__ O, int nseg)
{
  int wv = threadIdx.x >> 6, lane = threadIdx.x & 63;
  int seg = blockIdx.x * 4 + wv;
  if (seg >= nseg) return;
  int p0 = rp[seg], p1 = rp[seg + 1];
  if (p0 >= p1) return;
  float a0 = 0.f, a1 = 0.f;
  int j = p0;
  for (; j + 3 < p1; j += 4) {
    int s0 = ent[j], s1 = ent[j + 1], s2 = ent[j + 2], s3 = ent[j + 3];
    float2 v0 = ((const float2*)(SRC + (size_t)s0 * 128))[lane];
    float2 v1 = ((const float2*)(SRC + (size_t)s1 * 128))[lane];
    float2 v2 = ((const float2*)(SRC + (size_t)s2 * 128))[lane];
    float2 v3 = ((const float2*)(SRC + (size_t)s3 * 128))[lane];
    a0 += (v0.x + v1.x) + (v2.x + v3.x);
    a1 += (v0.y + v1.y) + (v2.y + v3.y);
  }
  for (; j < p1; ++j) {
    float2 v0 = ((const float2*)(SRC + (size_t)ent[j] * 128))[lane];
    a0 += v0.x; a1 += v0.y;
  }
  float sc = 1.f / fmaxf((float)(p1 - p0), 1.f);
  float2* orow = (float2*)(O + (size_t)seg * 128);
  float2 cur = orow[lane];
  cur.x += a0 * sc; cur.y += a1 * sc;
  orow[lane] = cur;
}

// ---------------- fused attention: online softmax + PV, one wave per node ----------------
__global__ __launch_bounds__(256)
void k_attn(const int* __restrict__ rp, const int* __restrict__ ent,
            const float* __restrict__ q, const float* __restrict__ kb,
            const float* __restrict__ vb, float* __restrict__ o, int nseg)
{
  int wv = threadIdx.x >> 6, lane = threadIdx.x & 63;
  int seg = blockIdx.x * 4 + wv;
  if (seg >= nseg) return;
  int p0 = rp[seg], p1 = rp[seg + 1];
  if (p0 >= p1) return;
  float2 q2 = ((const float2*)(q + (size_t)seg * 128))[lane];
  float m = -1e30f, l = 0.f, o0 = 0.f, o1 = 0.f;
  for (int j = p0; j < p1; ++j) {
    int s = ent[j];
    float2 k2 = ((const float2*)(kb + (size_t)s * 128))[lane];
    float d = fmaf(q2.x, k2.x, q2.y * k2.y);
    #pragma unroll
    for (int off = 1; off < 64; off <<= 1) d += __shfl_xor(d, off);
    float sc = d * 0.088388347648318447f;          // 1/sqrt(128)
    sc = sc > 0.f ? sc : 0.2f * sc;                // leaky 0.2
    float mn = fmaxf(m, sc);
    float scale = expf(m - mn);
    float e = expf(sc - mn);
    float2 v2 = ((const float2*)(vb + (size_t)s * 128))[lane];
    l  = l * scale + e;
    o0 = o0 * scale + e * v2.x;
    o1 = o1 * scale + e * v2.y;
    m = mn;
  }
  float inv = 1.f / fmaxf(l, 1e-9f);
  float2* orow = (float2*)(o + (size_t)seg * 128);
  float2 cur = orow[lane];
  cur.x += o0 * inv; cur.y += o1 * inv;
  orow[lane] = cur;
}

// ---------------- classifier + log_softmax ----------------
__global__ __launch_bounds__(256)
void k_out(const float* __restrict__ attn, const float* __restrict__ Wout,
           float* __restrict__ out, int n) {
  __shared__ float sW[128 * 64];
  for (int i = threadIdx.x; i < 128 * 64; i += 256) sW[i] = Wout[i];
  __syncthreads();
  int wave = threadIdx.x >> 6, lane = threadIdx.x & 63;
  int row = blockIdx.x * 4 + wave;
  if (row >= n) return;
  const float* a = attn + (size_t)row * 128;
  float z = 0.f;
  #pragma unroll 8
  for (int k = 0; k < 128; ++k) z = fmaf(a[k], sW[k * 64 + lane], z);
  float mx = z;
  #pragma unroll
  for (int off = 32; off; off >>= 1) mx = fmaxf(mx, __shfl_xor(mx, off));
  float ee = expf(z - mx);
  float ss = ee;
  #pragma unroll
  for (int off = 32; off; off >>= 1) ss += __shfl_xor(ss, off);
  out[(size_t)row * 64 + lane] = z - mx - logf(ss);
}

extern "C" void kernel_launch(void* const* d_in, const int* in_sizes, int n_in,
                              void* d_out, int out_size, void* d_ws, size_t ws_size,
                              hipStream_t stream) {
  (void)in_sizes; (void)n_in; (void)out_size;
  const float* x        = (const float*)d_in[0];
  const float* et       = (const float*)d_in[1];
  const int*   H0       = (const int*)d_in[2];
  const int*   H1       = H0 + Ee;
  const int*   src      = (const int*)d_in[3];
  const int*   dst      = src + Ee;
  const int*   src_lg   = (const int*)d_in[4];
  const int*   dst_lg   = src_lg + LGEe;
  const float* W_tsa1_s = (const float*)d_in[5];
  const float* W_tsa1_n = (const float*)d_in[6];
  const float* W_tsa2_s = (const float*)d_in[7];
  const float* W_tsa2_n = (const float*)d_in[8];
  const float* W_etn    = (const float*)d_in[9];
  const float* W_eg_lin = (const float*)d_in[10];
  const float* W_ea_s   = (const float*)d_in[11];
  const float* W_ea_n   = (const float*)d_in[12];
  const float* W_an1_s  = (const float*)d_in[13];
  const float* W_an1_n  = (const float*)d_in[14];
  const float* W_an2_s  = (const float*)d_in[15];
  const float* W_an2_n  = (const float*)d_in[16];
  const float* Wq       = (const float*)d_in[17];
  const float* Wk       = (const float*)d_in[18];
  const float* Wv       = (const float*)d_in[19];
  const float* W_out    = (const float*)d_in[20];
  float* out = (float*)d_out;

  // ---- workspace carve ----
  char* wp = (char*)d_ws;
  size_t avail = ws_size;
  auto alloc = [&](size_t bytes) -> void* {
    void* r = (void*)wp;
    size_t pad = (bytes + 255) & ~(size_t)255;
    wp += pad; avail = (avail >= pad) ? avail - pad : 0;
    return r;
  };
  const size_t NH = (size_t)Nn * 128;
  unsigned short* BUF = (unsigned short*)alloc((size_t)Ee * 128 * 2); // 204.8MB bf16 h1
  float* agg   = (float*)alloc(NH * 4);
  int* ptrA  = (int*)alloc(((size_t)Ee + 1) * 4);
  int* cntA  = (int*)alloc((size_t)Ee * 4);
  int* entA  = (int*)alloc((size_t)LGEe * 4);
  int* ptrB  = (int*)alloc(((size_t)Nn + 1) * 4);
  int* cntB  = (int*)alloc((size_t)Nn * 4);
  int* entBs = (int*)alloc((size_t)2 * LGEe * 4);
  float* entBw = (float*)alloc((size_t)2 * LGEe * 4);
  int* ptrC  = (int*)alloc(((size_t)Nn + 1) * 4);
  int* cntC  = (int*)alloc((size_t)Nn * 4);
  int* entC  = (int*)alloc((size_t)2 * Ee * 4);
  int* ptrD  = (int*)alloc(((size_t)Nn + 1) * 4);
  int* cntD  = (int*)alloc((size_t)Nn * 4);
  int* entD  = (int*)alloc((size_t)Ee * 4);
  float* rdegN = (float*)alloc((size_t)Nn * 4);
  int* bsum  = (int*)alloc(2048 * 4);
  if (avail == 0 && wp > (char*)d_ws + ws_size) return;  // ws too small: clean fail

  // node-phase f32 arrays overlay BUF (dead after agg is built): 8 x 25.6MB
  float* er  = (float*)BUF + 0 * NH;
  float* ae  = (float*)BUF + 1 * NH;
  float* hn  = (float*)BUF + 2 * NH;
  float* hn2 = (float*)BUF + 3 * NH;
  float* qb  = (float*)BUF + 4 * NH;
  float* kb  = (float*)BUF + 5 * NH;
  float* vb  = (float*)BUF + 6 * NH;
  float* tmp = (float*)BUF + 7 * NH;

  auto cdiv = [](long a, long b) { return (int)((a + b - 1) / b); };
  auto scan = [&](int* cnt, int* ptr, int n, int total) {
    int nb = cdiv(n, 1024);
    k_scan1<<<nb, 256, 0, stream>>>(cnt, ptr, bsum, n);
    k_scan2<<<1, 1024, 0, stream>>>(bsum, nb);
    k_scan3<<<cdiv(n, 256), 256, 0, stream>>>(ptr, bsum, n, total);
  };

  const int gLG = cdiv(LGEe, 256), gEe = cdiv(Ee, 256);

  // ---- CSR A: line-graph by dst_lg (E segments) ----
  hipMemsetAsync(cntA, 0, (size_t)Ee * 4, stream);
  k_count_direct<<<gLG, 256, 0, stream>>>(dst_lg, cntA, LGEe);
  scan(cntA, ptrA, Ee, LGEe);
  hipMemsetAsync(cntA, 0, (size_t)Ee * 4, stream);
  k_fillA<<<gLG, 256, 0, stream>>>(dst_lg, src_lg, ptrA, cntA, entA, LGEe);

  // ---- CSR B: composed H[b][dst_lg[m]] (N segments, 2*LGE entries) ----
  hipMemsetAsync(cntB, 0, (size_t)Nn * 4, stream);
  k_count_comp<<<gLG, 256, 0, stream>>>(H0, dst_lg, cntB, LGEe);
  k_count_comp<<<gLG, 256, 0, stream>>>(H1, dst_lg, cntB, LGEe);
  scan(cntB, ptrB, Nn, 2 * LGEe);
  hipMemsetAsync(cntB, 0, (size_t)Nn * 4, stream);
  k_fillB<<<gLG, 256, 0, stream>>>(H0, dst_lg, src_lg, ptrA, ptrB, cntB, entBs, entBw, LGEe);
  k_fillB<<<gLG, 256, 0, stream>>>(H1, dst_lg, src_lg, ptrA, ptrB, cntB, entBs, entBw, LGEe);

  // ---- CSR C: H incidence (N segments, 2*E entries, value = edge id) ----
  hipMemsetAsync(cntC, 0, (size_t)Nn * 4, stream);
  k_count_direct<<<gEe, 256, 0, stream>>>(H0, cntC, Ee);
  k_count_direct<<<gEe, 256, 0, stream>>>(H1, cntC, Ee);
  scan(cntC, ptrC, Nn, 2 * Ee);
  hipMemsetAsync(cntC, 0, (size_t)Nn * 4, stream);
  k_fillC<<<gEe, 256, 0, stream>>>(H0, ptrC, cntC, entC, Ee);
  k_fillC<<<gEe, 256, 0, stream>>>(H1, ptrC, cntC, entC, Ee);

  // ---- CSR D: raw graph by dst (N segments, E entries, value = src) ----
  hipMemsetAsync(cntD, 0, (size_t)Nn * 4, stream);
  k_count_direct<<<gEe, 256, 0, stream>>>(dst, cntD, Ee);
  scan(cntD, ptrD, Nn, Ee);
  hipMemsetAsync(cntD, 0, (size_t)Nn * 4, stream);
  k_fillD<<<gEe, 256, 0, stream>>>(dst, src, ptrD, cntD, entD, Ee);
  k_rdeg<<<cdiv(Nn, 256), 256, 0, stream>>>(ptrC, rdegN, Nn);

  const int gN128 = cdiv(Nn, 128);      // 391
  const int gN32  = cdiv(Nn, 32);       // 1563
  const int gW    = cdiv(Nn, 4);        // 12500

  // ---- TSA layer 1, fused self+nbr -> BUF (bf16, pre-relu) ----
  k_tsa1<<<Ee / 64, 256, 0, stream>>>(et, ptrA, entA, W_tsa1_s, W_tsa1_n, BUF);

  // ---- TSA layer 2 + EdgeToNode fused at N-scale (agg = P@W2s + Q@W2n) ----
  k_gg2<<<gN32, 256, 0, stream>>>(Nn, ptrC, entC, nullptr, 0, BUF, W_tsa2_s, agg, 0);
  k_gg2<<<gN32, 256, 0, stream>>>(Nn, ptrB, entBs, entBw, 0, BUF, W_tsa2_n, agg, 1);
  k_gemm128<<<gN128, 256, 0, stream>>>(Nn, agg, 128, W_etn, rdegN, 0, 2, tmp);
  k_gemm128<<<gN128, 256, 0, stream>>>(Nn, tmp, 128, W_eg_lin, nullptr, 0, 0, er);

  // ---- edge_aggr SAGE ----
  k_gemm128<<<gN128, 256, 0, stream>>>(Nn, er, 128, W_ea_s, nullptr, 0, 0, ae);
  k_gemm128<<<gN128, 256, 0, stream>>>(Nn, er, 128, W_ea_n, nullptr, 0, 0, tmp);
  k_gsum<<<gW, 256, 0, stream>>>(ptrD, entD, tmp, ae, Nn);

  // ---- attr_node_model (hn kept pre-relu; relu applied on read) ----
  k_gemm128<<<gN128, 256, 0, stream>>>(Nn, x, 256, W_an1_s, nullptr, 0, 0, hn);
  k_gemm128<<<gN128, 256, 0, stream>>>(Nn, x, 256, W_an1_n, nullptr, 0, 0, tmp);
  k_gsum<<<gW, 256, 0, stream>>>(ptrD, entD, tmp, hn, Nn);
  k_gemm128<<<gN128, 256, 0, stream>>>(Nn, hn, 128, W_an2_s, nullptr, 1, 0, hn2);
  k_gemm128<<<gN128, 256, 0, stream>>>(Nn, hn, 128, W_an2_n, nullptr, 1, 0, tmp);
  k_gsum<<<gW, 256, 0, stream>>>(ptrD, entD, tmp, hn2, Nn);

  // ---- MixAttention (fused online softmax; out accumulated into hn2) ----
  k_gemm128<<<gN128, 256, 0, stream>>>(Nn, hn2, 128, Wq, nullptr, 0, 0, qb);
  k_gemm128<<<gN128, 256, 0, stream>>>(Nn, ae, 128, Wk, nullptr, 0, 0, kb);
  k_gemm128<<<gN128, 256, 0, stream>>>(Nn, ae, 128, Wv, nullptr, 0, 0, vb);
  k_attn<<<gW, 256, 0, stream>>>(ptrD, entD, qb, kb, vb, hn2, Nn);

  // ---- classifier + log_softmax ----
  k_out<<<gW, 256, 0, stream>>>(hn2, W_out, out, Nn);
}